// Round 5
// baseline (785.816 us; speedup 1.0000x reference)
//
#include <hip/hip_runtime.h>

// BlockSparseLinear: out[M,N] = 2 * (x[M,K] @ (W .* mask)^T) + bias[N]
// M = 16384, N = 4096, K = 4096, mask 32x32 blocks over (128,128).
// v5: delivery-optimized. Tiles 128x512 (A-traffic 1.07 GiB), bn = blockIdx&7
// pins one 4-MiB B-panel per XCD (L2-resident). B frags load L2->regs
// directly (no LDS), double-buffered 1 tile ahead, with wave-uniform
// sparsity branches (skip ~50% of B loads + MFMA). LDS holds only A
// (3-slot ring, 24 KiB), staged via global_load_lds with source-side
// XOR swizzle from linear xb. Top-of-tile wait is vmcnt(1): the single
// A-stage is always the newest outstanding VMEM op, so variable B-load
// counts are safe.

typedef short s16x8 __attribute__((ext_vector_type(8)));
typedef float f32x4 __attribute__((ext_vector_type(4)));
typedef unsigned short u16;
typedef unsigned long long u64;

#define M_TOT 16384
#define N_TOT 4096
#define K_TOT 4096
#define MASK_DIM 128
#define NT 128         // K tiles of 32
#define LDS_STRIDE 72  // legacy fallback kernel only

__device__ __forceinline__ u16 f2bf(float f) {
  union { float f; unsigned u; } v; v.f = f;
  unsigned r = v.u + 0x7FFFu + ((v.u >> 16) & 1u);  // round-to-nearest-even
  return (u16)(r >> 16);
}

__device__ __forceinline__ void load16_to_lds(const u16* g, u16* l) {
  __builtin_amdgcn_global_load_lds(
      (const __attribute__((address_space(1))) void*)g,
      (__attribute__((address_space(3))) void*)l, 16, 0, 0);
}

// ---------------------------------------------------------------------------
// Mask normalization (format auto-detect) + bit-pack (maskbits[row][4] u32).
// ---------------------------------------------------------------------------
__global__ void prep_mask_kernel(const unsigned char* __restrict__ m,
                                 unsigned char* __restrict__ outm,
                                 unsigned* __restrict__ outbits) {
  __shared__ int s_ok[4];
  const int t = threadIdx.x;
  unsigned v = reinterpret_cast<const unsigned*>(m)[t];
  bool wordlike = (v <= 1u) || (v == 0x3F800000u);
  unsigned long long b = __ballot(wordlike);
  if ((t & 63) == 0) s_ok[t >> 6] = (b == ~0ull) ? 1 : 0;
  __syncthreads();
  const bool word_fmt = s_ok[0] && s_ok[1] && s_ok[2] && s_ok[3];
  for (int i = t; i < MASK_DIM * MASK_DIM; i += 256) {
    bool nz = word_fmt ? (reinterpret_cast<const unsigned*>(m)[i] != 0u)
                       : (m[i] != 0);
    outm[i] = nz ? 1 : 0;
  }
  __syncthreads();
  for (int i = t; i < MASK_DIM * 4; i += 256) {
    const int r = i >> 2, w = i & 3;
    unsigned acc = 0;
    for (int bit = 0; bit < 32; ++bit)
      acc |= (unsigned)(outm[r * MASK_DIM + w * 32 + bit] != 0) << bit;
    outbits[i] = acc;
  }
}

// ---------------------------------------------------------------------------
// x fp32 [M][K] -> bf16 linear.
// ---------------------------------------------------------------------------
__global__ void prep_x_kernel(const float* __restrict__ x,
                              u16* __restrict__ xb) {
  const size_t e = ((size_t)blockIdx.x * 256 + threadIdx.x) * 8;
  const float4 v0 = *reinterpret_cast<const float4*>(x + e);
  const float4 v1 = *reinterpret_cast<const float4*>(x + e + 4);
  s16x8 b;
  b[0] = (short)f2bf(v0.x); b[1] = (short)f2bf(v0.y);
  b[2] = (short)f2bf(v0.z); b[3] = (short)f2bf(v0.w);
  b[4] = (short)f2bf(v1.x); b[5] = (short)f2bf(v1.y);
  b[6] = (short)f2bf(v1.z); b[7] = (short)f2bf(v1.w);
  *reinterpret_cast<s16x8*>(xb + e) = b;
}

// ---------------------------------------------------------------------------
// W fp32 [N][K] -> masked bf16 linear.
// ---------------------------------------------------------------------------
__global__ void prep_w_kernel(const float* __restrict__ w,
                              const unsigned char* __restrict__ mask8,
                              u16* __restrict__ wb) {
  const size_t e = ((size_t)blockIdx.x * blockDim.x + threadIdx.x) * 4;
  const int n = (int)(e >> 12);
  const int k = (int)(e & 4095);
  const float4 v = *reinterpret_cast<const float4*>(w + e);
  ushort4 bvec;
  if (mask8[(n >> 5) * MASK_DIM + (k >> 5)]) {
    bvec.x = f2bf(v.x); bvec.y = f2bf(v.y); bvec.z = f2bf(v.z); bvec.w = f2bf(v.w);
  } else {
    bvec.x = 0; bvec.y = 0; bvec.z = 0; bvec.w = 0;
  }
  *reinterpret_cast<ushort4*>(wb + e) = bvec;
}

// ---------------------------------------------------------------------------
// v5 GEMM: tiles 128x512, 8 waves (1M x 8N), BK=32.
// A: LDS 3-slot ring via global_load_lds (src-swizzled). B: L2->regs direct.
// ---------------------------------------------------------------------------
__global__ __launch_bounds__(512, 2) void gemm_bL2_kernel(
    const u16* __restrict__ xb, const u16* __restrict__ wb,
    const unsigned* __restrict__ maskbits,
    const float* __restrict__ bias, float* __restrict__ out) {
  __shared__ __align__(16) u16 As[3 * 4096];  // 3 slots x (128 rows x 32 elems)

  const int tid = threadIdx.x;
  const int lane = tid & 63;
  const int w = tid >> 6;   // wave -> 64-col group
  const int lrow = lane & 15;
  const int g = lane >> 4;

  const int id = blockIdx.x;
  const int bmb = (id >> 3) << 7;  // row base (128-tiles)
  const int bnb = (id & 7) << 9;   // col base: one bn panel per XCD

  // A staging: thread -> row tid>>2, phys chunk tid&3; source swizzled.
  const int sr = tid >> 2;
  const int sc = tid & 3;
  const u16* asrc = xb + (size_t)(bmb + sr) * K_TOT +
                    (size_t)(((sc ^ ((sr >> 1) & 3)) << 3));
  u16* adst = As + w * 512;  // wave-uniform; HW adds lane*16B

  // A frag read: byte offset within slot for frag m = m*1024 + abyte.
  const int abyte = lrow * 64 + (((g ^ ((lrow >> 1) & 3))) << 4);

  // B frag row bases (per lane), linear wb.
  const u16* brow0 = wb + (size_t)(bnb + w * 64 + 0 * 16 + lrow) * K_TOT + g * 8;
  const u16* brow1 = wb + (size_t)(bnb + w * 64 + 1 * 16 + lrow) * K_TOT + g * 8;
  const u16* brow2 = wb + (size_t)(bnb + w * 64 + 2 * 16 + lrow) * K_TOT + g * 8;
  const u16* brow3 = wb + (size_t)(bnb + w * 64 + 3 * 16 + lrow) * K_TOT + g * 8;

  // Wave-uniform sparsity bits (2 mask rows per wave) in SGPRs.
  const unsigned* mbp = maskbits + (((bnb + w * 64) >> 5) << 2);
  const unsigned q0 = __builtin_amdgcn_readfirstlane(mbp[0]);
  const unsigned q1 = __builtin_amdgcn_readfirstlane(mbp[1]);
  const unsigned q2 = __builtin_amdgcn_readfirstlane(mbp[2]);
  const unsigned q3 = __builtin_amdgcn_readfirstlane(mbp[3]);
  const unsigned q4 = __builtin_amdgcn_readfirstlane(mbp[4]);
  const unsigned q5 = __builtin_amdgcn_readfirstlane(mbp[5]);
  const unsigned q6 = __builtin_amdgcn_readfirstlane(mbp[6]);
  const unsigned q7 = __builtin_amdgcn_readfirstlane(mbp[7]);
  const u64 m0lo = (u64)q0 | ((u64)q1 << 32);
  const u64 m0hi = (u64)q2 | ((u64)q3 << 32);
  const u64 m1lo = (u64)q4 | ((u64)q5 << 32);
  const u64 m1hi = (u64)q6 | ((u64)q7 << 32);

#define BIT0(tt) ((int)((((tt)&64) ? m0hi : m0lo) >> ((tt)&63)) & 1)
#define BIT1(tt) ((int)((((tt)&64) ? m1hi : m1lo) >> ((tt)&63)) & 1)

  f32x4 acc[8][4] = {};
  s16x8 bA[4], bB[4];

  // Prologue: A(0), B(0), A(1)  [issue order matters: A(1) must be newest].
  load16_to_lds(asrc + 0 * 32, adst + 0 * 4096);
  {
    const int b00 = BIT0(0), b01 = BIT1(0);
    if (b00) { bA[0] = *(const s16x8*)(brow0); bA[1] = *(const s16x8*)(brow1); }
    if (b01) { bA[2] = *(const s16x8*)(brow2); bA[3] = *(const s16x8*)(brow3); }
  }
  load16_to_lds(asrc + 1 * 32, adst + 1 * 4096);

#define BODY(t, BC, BN)                                                       \
  {                                                                           \
    asm volatile("s_waitcnt vmcnt(1)" ::: "memory");                          \
    __builtin_amdgcn_s_barrier();                                             \
    const int tt1 = ((t) + 1 < NT) ? (t) + 1 : NT - 1;                        \
    const int nb0 = BIT0(tt1), nb1 = BIT1(tt1);                               \
    if (nb0) {                                                                \
      BN[0] = *(const s16x8*)(brow0 + tt1 * 32);                              \
      BN[1] = *(const s16x8*)(brow1 + tt1 * 32);                              \
    }                                                                         \
    if (nb1) {                                                                \
      BN[2] = *(const s16x8*)(brow2 + tt1 * 32);                              \
      BN[3] = *(const s16x8*)(brow3 + tt1 * 32);                              \
    }                                                                         \
    {                                                                         \
      const int tt2 = ((t) + 2 < NT) ? (t) + 2 : NT - 1;                      \
      load16_to_lds(asrc + tt2 * 32, adst + (((t) + 2) % 3) * 4096);          \
    }                                                                         \
    const int cb0 = BIT0(t), cb1 = BIT1(t);                                   \
    if (cb0 | cb1) {                                                          \
      s16x8 af[8];                                                            \
      const char* ap = (const char*)As + ((t) % 3) * 8192;                    \
      _Pragma("unroll") for (int m = 0; m < 8; ++m)                           \
          af[m] = *(const s16x8*)(ap + m * 1024 + abyte);                     \
      asm volatile("s_waitcnt lgkmcnt(0)" ::: "memory");                      \
      __builtin_amdgcn_sched_barrier(0);                                      \
      __builtin_amdgcn_s_setprio(1);                                          \
      if (cb0) {                                                              \
        _Pragma("unroll") for (int m = 0; m < 8; ++m) {                       \
          acc[m][0] = __builtin_amdgcn_mfma_f32_16x16x32_bf16(                \
              af[m], BC[0], acc[m][0], 0, 0, 0);                              \
          acc[m][1] = __builtin_amdgcn_mfma_f32_16x16x32_bf16(                \
              af[m], BC[1], acc[m][1], 0, 0, 0);                              \
        }                                                                     \
      }                                                                       \
      if (cb1) {                                                              \
        _Pragma("unroll") for (int m = 0; m < 8; ++m) {                       \
          acc[m][2] = __builtin_amdgcn_mfma_f32_16x16x32_bf16(                \
              af[m], BC[2], acc[m][2], 0, 0, 0);                              \
          acc[m][3] = __builtin_amdgcn_mfma_f32_16x16x32_bf16(                \
              af[m], BC[3], acc[m][3], 0, 0, 0);                              \
        }                                                                     \
      }                                                                       \
      __builtin_amdgcn_s_setprio(0);                                          \
    }                                                                         \
  }

  for (int t = 0; t < NT; t += 2) {
    BODY(t, bA, bB);
    BODY(t + 1, bB, bA);
  }
#undef BODY
#undef BIT0
#undef BIT1

  // Epilogue: out = 2*acc + bias. C/D frag: col = lane&15, row = g*4 + j.
#pragma unroll
  for (int n = 0; n < 4; ++n) {
    const int gcol = bnb + w * 64 + n * 16 + lrow;
    const float bv = bias[gcol];
#pragma unroll
    for (int m = 0; m < 8; ++m) {
      const int grow = bmb + m * 16 + (g << 2);
#pragma unroll
      for (int j = 0; j < 4; ++j)
        out[(size_t)(grow + j) * N_TOT + gcol] = 2.0f * acc[m][n][j] + bv;
    }
  }
}

// ---------------------------------------------------------------------------
// Legacy reg-staged GEMM (fallback when ws can't hold xb).
// ---------------------------------------------------------------------------
template <bool PREPPED>
__global__ __launch_bounds__(256) void gemm_kernel(
    const float* __restrict__ x, const u16* __restrict__ wb,
    const float* __restrict__ wf, const unsigned char* __restrict__ mask8,
    const float* __restrict__ bias, float* __restrict__ out) {
  __shared__ __align__(16) u16 Asl[128 * LDS_STRIDE];
  __shared__ __align__(16) u16 Bsl[128 * LDS_STRIDE];

  const int tid = threadIdx.x;
  const int lane = tid & 63;
  const int wave = tid >> 6;
  const int wr = wave >> 1;
  const int wcn = wave & 1;

  int id = blockIdx.x;
  const int cpx = gridDim.x >> 3;
  id = (id & 7) * cpx + (id >> 3);
  const int bm = (id >> 5) << 7;
  const int bn = (id & 31) << 7;

  const int arow = tid >> 4;
  const int acol = (tid & 15) << 2;
  const int brow = tid >> 3;
  const int bcol = (tid & 7) << 3;

  const int lrow = lane & 15;
  const int lgo = (lane >> 4) << 3;

  f32x4 acc[4][4] = {};

  for (int k0 = 0; k0 < K_TOT; k0 += 64) {
#pragma unroll
    for (int r = 0; r < 8; ++r) {
      const int row = arow + r * 16;
      const float4 v = *reinterpret_cast<const float4*>(
          x + (size_t)(bm + row) * K_TOT + k0 + acol);
      ushort4 bvec;
      bvec.x = f2bf(v.x); bvec.y = f2bf(v.y); bvec.z = f2bf(v.z); bvec.w = f2bf(v.w);
      *reinterpret_cast<ushort4*>(&Asl[row * LDS_STRIDE + acol]) = bvec;
    }
    if (PREPPED) {
#pragma unroll
      for (int r = 0; r < 4; ++r) {
        const int row = brow + r * 32;
        const s16x8 v = *reinterpret_cast<const s16x8*>(
            wb + (size_t)(bn + row) * K_TOT + k0 + bcol);
        *reinterpret_cast<s16x8*>(&Bsl[row * LDS_STRIDE + bcol]) = v;
      }
    } else {
#pragma unroll
      for (int r = 0; r < 8; ++r) {
        const int row = arow + r * 16;
        const float4 v = *reinterpret_cast<const float4*>(
            wf + (size_t)(bn + row) * K_TOT + k0 + acol);
        ushort4 bvec;
        bvec.x = 0; bvec.y = 0; bvec.z = 0; bvec.w = 0;
        if (mask8[((bn + row) >> 5) * MASK_DIM + ((k0 + acol) >> 5)]) {
          bvec.x = f2bf(v.x); bvec.y = f2bf(v.y); bvec.z = f2bf(v.z); bvec.w = f2bf(v.w);
        }
        *reinterpret_cast<ushort4*>(&Bsl[row * LDS_STRIDE + acol]) = bvec;
      }
    }
    __syncthreads();

#pragma unroll
    for (int ks = 0; ks < 2; ++ks) {
      s16x8 af[4], bfv[4];
#pragma unroll
      for (int m = 0; m < 4; ++m)
        af[m] = *reinterpret_cast<const s16x8*>(
            &Asl[(wr * 64 + m * 16 + lrow) * LDS_STRIDE + ks * 32 + lgo]);
#pragma unroll
      for (int n = 0; n < 4; ++n)
        bfv[n] = *reinterpret_cast<const s16x8*>(
            &Bsl[(wcn * 64 + n * 16 + lrow) * LDS_STRIDE + ks * 32 + lgo]);
#pragma unroll
      for (int m = 0; m < 4; ++m)
#pragma unroll
        for (int n = 0; n < 4; ++n)
          acc[m][n] = __builtin_amdgcn_mfma_f32_16x16x32_bf16(af[m], bfv[n],
                                                              acc[m][n], 0, 0, 0);
    }
    __syncthreads();
  }

#pragma unroll
  for (int n = 0; n < 4; ++n) {
    const int gcol = bn + wcn * 64 + n * 16 + lrow;
    const float bv = bias[gcol];
#pragma unroll
    for (int m = 0; m < 4; ++m) {
      const int grow = bm + wr * 64 + m * 16 + ((lane >> 4) << 2);
#pragma unroll
      for (int j = 0; j < 4; ++j) {
        out[(size_t)(grow + j) * N_TOT + gcol] = 2.0f * acc[m][n][j] + bv;
      }
    }
  }
}

extern "C" void kernel_launch(void* const* d_in, const int* in_sizes, int n_in,
                              void* d_out, int out_size, void* d_ws, size_t ws_size,
                              hipStream_t stream) {
  const float* x = (const float*)d_in[0];
  const float* w = (const float*)d_in[1];
  const float* bias = (const float*)d_in[2];
  const unsigned char* mask_raw = (const unsigned char*)d_in[3];
  float* out = (float*)d_out;

  unsigned char* ws_mask = (unsigned char*)d_ws;            // 16 KiB mask8
  unsigned* ws_bits = (unsigned*)((char*)d_ws + 16384);     // 2 KiB bitmask
  u16* wb = (u16*)((char*)d_ws + 65536);                    // 32 MiB bf16 W
  u16* xb = (u16*)((char*)d_ws + 65536 +
                   (size_t)N_TOT * K_TOT * sizeof(u16));    // 128 MiB bf16 x
  const size_t need_w = 65536 + (size_t)N_TOT * K_TOT * sizeof(u16);
  const size_t need_full = need_w + (size_t)M_TOT * K_TOT * sizeof(u16);

  prep_mask_kernel<<<1, 256, 0, stream>>>(mask_raw, ws_mask, ws_bits);

  if (ws_size >= need_full) {
    prep_w_kernel<<<(N_TOT * K_TOT) / (256 * 4), 256, 0, stream>>>(w, ws_mask, wb);
    prep_x_kernel<<<(M_TOT * K_TOT) / (256 * 8), 256, 0, stream>>>(x, xb);
    gemm_bL2_kernel<<<(M_TOT / 128) * (N_TOT / 512), 512, 0, stream>>>(
        xb, wb, ws_bits, bias, out);
  } else if (ws_size >= need_w) {
    prep_w_kernel<<<(N_TOT * K_TOT) / (256 * 4), 256, 0, stream>>>(w, ws_mask, wb);
    gemm_kernel<true><<<(M_TOT / 128) * (N_TOT / 128), 256, 0, stream>>>(
        x, wb, nullptr, nullptr, bias, out);
  } else {
    gemm_kernel<false><<<(M_TOT / 128) * (N_TOT / 128), 256, 0, stream>>>(
        x, nullptr, w, ws_mask, bias, out);
  }
}

// Round 6
// 583.234 us; speedup vs baseline: 1.3473x; 1.3473x over previous
//
#include <hip/hip_runtime.h>

// BlockSparseLinear: out[M,N] = 2 * (x[M,K] @ (W .* mask)^T) + bias[N]
// M = 16384, N = 4096, K = 4096, mask 32x32 blocks over (128,128).
// v6 = round-4 structure (256x256 tile, BK=32, 8 waves 2Mx4N, 4-slot LDS
// ring 128 KiB, prefetch depth 3, counted vmcnt(8), pre-swizzled bf16
// operands in d_ws) + two deltas:
//   (1) B-staging sparsity skip via SOURCE-POINTER REDIRECT (skipped B
//       loads re-read the A address: L1-hit, no L3 delivery, op count
//       unchanged so counted vmcnt stays valid; skipped LDS regions are
//       never read because MFMA skip uses the same mask bits).
//   (2) single-phase tile: one barrier + one lgkmcnt per K-tile
//       (4-slot hazard analysis: stage(t+3) writes slot (t-1)&3 whose
//       reads completed before this tile's top barrier).

typedef short s16x8 __attribute__((ext_vector_type(8)));
typedef float f32x4 __attribute__((ext_vector_type(4)));
typedef unsigned short u16;
typedef unsigned long long u64;

#define M_TOT 16384
#define N_TOT 4096
#define K_TOT 4096
#define MASK_DIM 128
#define NT 128         // K tiles of 32
#define LDS_STRIDE 72  // legacy fallback kernel only

__device__ __forceinline__ u16 f2bf(float f) {
  union { float f; unsigned u; } v; v.f = f;
  unsigned r = v.u + 0x7FFFu + ((v.u >> 16) & 1u);  // round-to-nearest-even
  return (u16)(r >> 16);
}

__device__ __forceinline__ void load16_to_lds(const u16* g, u16* l) {
  __builtin_amdgcn_global_load_lds(
      (const __attribute__((address_space(1))) void*)g,
      (__attribute__((address_space(3))) void*)l, 16, 0, 0);
}

// ---------------------------------------------------------------------------
// Mask normalization (format auto-detect) + bit-pack (maskbits[row][4] u32).
// ---------------------------------------------------------------------------
__global__ void prep_mask_kernel(const unsigned char* __restrict__ m,
                                 unsigned char* __restrict__ outm,
                                 unsigned* __restrict__ outbits) {
  __shared__ int s_ok[4];
  const int t = threadIdx.x;
  unsigned v = reinterpret_cast<const unsigned*>(m)[t];
  bool wordlike = (v <= 1u) || (v == 0x3F800000u);
  unsigned long long b = __ballot(wordlike);
  if ((t & 63) == 0) s_ok[t >> 6] = (b == ~0ull) ? 1 : 0;
  __syncthreads();
  const bool word_fmt = s_ok[0] && s_ok[1] && s_ok[2] && s_ok[3];
  for (int i = t; i < MASK_DIM * MASK_DIM; i += 256) {
    bool nz = word_fmt ? (reinterpret_cast<const unsigned*>(m)[i] != 0u)
                       : (m[i] != 0);
    outm[i] = nz ? 1 : 0;
  }
  __syncthreads();
  for (int i = t; i < MASK_DIM * 4; i += 256) {
    const int r = i >> 2, w = i & 3;
    unsigned acc = 0;
    for (int bit = 0; bit < 32; ++bit)
      acc |= (unsigned)(outm[r * MASK_DIM + w * 32 + bit] != 0) << bit;
    outbits[i] = acc;
  }
}

// ---------------------------------------------------------------------------
// x fp32 [M][K] -> bf16, pre-swizzled: within each 32-elem K-tile (64B), 16B
// chunk c goes to slot c ^ ((row>>1)&3).
// ---------------------------------------------------------------------------
__global__ void prep_x_swz_kernel(const float* __restrict__ x,
                                  u16* __restrict__ xb) {
  const size_t t = (size_t)blockIdx.x * 256 + threadIdx.x;  // 16B-chunk index
  const size_t row = t >> 9;        // 512 chunks per 4096-elem row
  const int wc = (int)(t & 511);
  const int blk = wc >> 2;          // K-tile 0..127
  const int c = wc & 3;             // chunk within tile
  const float4 v0 = *reinterpret_cast<const float4*>(x + row * K_TOT + wc * 8);
  const float4 v1 = *reinterpret_cast<const float4*>(x + row * K_TOT + wc * 8 + 4);
  s16x8 b;
  b[0] = (short)f2bf(v0.x); b[1] = (short)f2bf(v0.y);
  b[2] = (short)f2bf(v0.z); b[3] = (short)f2bf(v0.w);
  b[4] = (short)f2bf(v1.x); b[5] = (short)f2bf(v1.y);
  b[6] = (short)f2bf(v1.z); b[7] = (short)f2bf(v1.w);
  *reinterpret_cast<s16x8*>(xb + row * K_TOT + blk * 32 +
                            (size_t)((c ^ (((int)row >> 1) & 3)) * 8)) = b;
}

// ---------------------------------------------------------------------------
// W fp32 [N][K] -> masked bf16, pre-swizzled (same scheme).
// ---------------------------------------------------------------------------
__global__ void prep_w_swz_kernel(const float* __restrict__ w,
                                  const unsigned char* __restrict__ mask8,
                                  u16* __restrict__ wb) {
  const size_t t = (size_t)blockIdx.x * 256 + threadIdx.x;
  const size_t row = t >> 9;
  const int wc = (int)(t & 511);
  const int blk = wc >> 2;
  const int c = wc & 3;
  s16x8 b = {};
  if (mask8[((int)row >> 5) * MASK_DIM + blk]) {
    const float4 v0 = *reinterpret_cast<const float4*>(w + row * K_TOT + wc * 8);
    const float4 v1 = *reinterpret_cast<const float4*>(w + row * K_TOT + wc * 8 + 4);
    b[0] = (short)f2bf(v0.x); b[1] = (short)f2bf(v0.y);
    b[2] = (short)f2bf(v0.z); b[3] = (short)f2bf(v0.w);
    b[4] = (short)f2bf(v1.x); b[5] = (short)f2bf(v1.y);
    b[6] = (short)f2bf(v1.z); b[7] = (short)f2bf(v1.w);
  }
  *reinterpret_cast<s16x8*>(wb + row * K_TOT + blk * 32 +
                            (size_t)((c ^ (((int)row >> 1) & 3)) * 8)) = b;
}

// ---------------------------------------------------------------------------
// Legacy linear prep_w (for the ws-fits-W-only fallback path).
// ---------------------------------------------------------------------------
__global__ void prep_w_kernel(const float* __restrict__ w,
                              const unsigned char* __restrict__ mask8,
                              u16* __restrict__ wb) {
  const size_t e = ((size_t)blockIdx.x * blockDim.x + threadIdx.x) * 4;
  const int n = (int)(e >> 12);
  const int k = (int)(e & 4095);
  const float4 v = *reinterpret_cast<const float4*>(w + e);
  ushort4 bvec;
  if (mask8[(n >> 5) * MASK_DIM + (k >> 5)]) {
    bvec.x = f2bf(v.x); bvec.y = f2bf(v.y); bvec.z = f2bf(v.z); bvec.w = f2bf(v.w);
  } else {
    bvec.x = 0; bvec.y = 0; bvec.z = 0; bvec.w = 0;
  }
  *reinterpret_cast<ushort4*>(wb + e) = bvec;
}

// ---------------------------------------------------------------------------
// v6 GEMM: 256x256, BK=32, 4-slot ring, counted vmcnt, B-stage redirect skip,
// single-phase tiles.  C = 2 * A @ B^T + bias.
// ---------------------------------------------------------------------------
__global__ __launch_bounds__(512, 2) void gemm8_kernel(
    const u16* __restrict__ xb, const u16* __restrict__ wb,
    const unsigned* __restrict__ maskbits,
    const float* __restrict__ bias, float* __restrict__ out) {
  extern __shared__ __align__(16) u16 lds[];  // A[4][256][32] | B[4][256][32]

  const int tid = threadIdx.x;
  const int lane = tid & 63;
  const int w = tid >> 6;
  const int wr = w >> 2;   // 0..1: rows [wr*128, +128)
  const int wc = w & 3;    // 0..3: cols [wc*64, +64)
  const int lrow = lane & 15;
  const int g = lane >> 4;
  const int kphys = ((g ^ ((lrow >> 1) & 3)) << 4);  // physical 16B chunk byte

  // XCD-aware bijective swizzle (grid = 1024, divisible by 8).
  int id = blockIdx.x;
  id = (id & 7) * (gridDim.x >> 3) + (id >> 3);
  const int bm = (id >> 4) << 8;  // 64 m-tiles
  const int bn = (id & 15) << 8;  // 16 n-tiles

  const char* ldsb = (const char*)lds;

  // ---- wave-uniform mask bits in SGPRs -----------------------------------
  // Compute bits: wave (wr,wc) covers B rows [wc*64, wc*64+64) -> mask rows
  // (bn>>5)+wc*2 (cols +0..31) and +1 (cols +32..63).
  const unsigned* cp = maskbits + (((bn >> 5) + wc * 2) << 2);
  const u64 m0lo = (u64)__builtin_amdgcn_readfirstlane(cp[0]) |
                   ((u64)__builtin_amdgcn_readfirstlane(cp[1]) << 32);
  const u64 m0hi = (u64)__builtin_amdgcn_readfirstlane(cp[2]) |
                   ((u64)__builtin_amdgcn_readfirstlane(cp[3]) << 32);
  const u64 m1lo = (u64)__builtin_amdgcn_readfirstlane(cp[4]) |
                   ((u64)__builtin_amdgcn_readfirstlane(cp[5]) << 32);
  const u64 m1hi = (u64)__builtin_amdgcn_readfirstlane(cp[6]) |
                   ((u64)__builtin_amdgcn_readfirstlane(cp[7]) << 32);
  // Staging bits: wave w stages B rows [w*16, w*16+16) (op0) and +128 (op1)
  // -> mask rows (bn>>5)+(w>>1) and +4.
  const unsigned* sp0 = maskbits + (((bn >> 5) + (w >> 1)) << 2);
  const unsigned* sp1 = maskbits + (((bn >> 5) + 4 + (w >> 1)) << 2);
  const u64 sg0lo = (u64)__builtin_amdgcn_readfirstlane(sp0[0]) |
                    ((u64)__builtin_amdgcn_readfirstlane(sp0[1]) << 32);
  const u64 sg0hi = (u64)__builtin_amdgcn_readfirstlane(sp0[2]) |
                    ((u64)__builtin_amdgcn_readfirstlane(sp0[3]) << 32);
  const u64 sg1lo = (u64)__builtin_amdgcn_readfirstlane(sp1[0]) |
                    ((u64)__builtin_amdgcn_readfirstlane(sp1[1]) << 32);
  const u64 sg1hi = (u64)__builtin_amdgcn_readfirstlane(sp1[2]) |
                    ((u64)__builtin_amdgcn_readfirstlane(sp1[3]) << 32);

  // Staging geometry: thread -> row tid>>2, 16B chunk tid&3.
  const int sr = tid >> 2;
  const int sc8 = (tid & 3) * 8;
  const u16* gaBase = xb + (size_t)(bm + sr) * K_TOT + sc8;
  const u16* ga2Base = gaBase + (size_t)128 * K_TOT;
  const u16* gb0Base = wb + (size_t)(bn + sr) * K_TOT + sc8;
  const u16* gb1Base = gb0Base + (size_t)128 * K_TOT;

  f32x4 acc[8][4] = {};

  auto stage = [&](int t) {
    const int s = t & 3;
    const int k0 = t << 5;
    const int sh = t & 63;
    const u64 s0 = (t & 64) ? sg0hi : sg0lo;
    const u64 s1 = (t & 64) ? sg1hi : sg1lo;
    const u16* ga = gaBase + k0;
    const u16* ga2 = ga2Base + k0;
    // Redirect skipped B loads to the A source (L1-hit dummy): op count and
    // LDS-dest layout stay fixed, so counted vmcnt remains valid.
    const u16* gb0 = ((int)((s0 >> sh) & 1)) ? gb0Base + k0 : ga;
    const u16* gb1 = ((int)((s1 >> sh) & 1)) ? gb1Base + k0 : ga2;
    u16* la = lds + s * 8192 + w * 512;            // wave-uniform dest base
    u16* lb = lds + 32768 + s * 8192 + w * 512;
    load16_to_lds(ga, la);
    load16_to_lds(ga2, la + 4096);
    load16_to_lds(gb0, lb);
    load16_to_lds(gb1, lb + 4096);
  };

  // Prologue: fill pipeline 3 deep (12 loads in flight).
  stage(0);
  stage(1);
  stage(2);

#define TILE(t, VMSTR)                                                        \
  {                                                                           \
    const int s_ = (t) & 3;                                                   \
    const int abase = s_ * 16384;                                             \
    const int bbase = 65536 + s_ * 16384;                                     \
    asm volatile("s_waitcnt " VMSTR ::: "memory");                            \
    __builtin_amdgcn_s_barrier();                                             \
    if ((t) <= NT - 4) stage((t) + 3);                                        \
    const int sh = (t) & 63;                                                  \
    const u64 sel0 = ((t) & 64) ? m0hi : m0lo;                                \
    const u64 sel1 = ((t) & 64) ? m1hi : m1lo;                                \
    const int b0 = (int)((sel0 >> sh) & 1);                                   \
    const int b1 = (int)((sel1 >> sh) & 1);                                   \
    if (b0 | b1) {                                                            \
      s16x8 af[8];                                                            \
      _Pragma("unroll") for (int m = 0; m < 8; ++m)                           \
          af[m] = *(const s16x8*)(ldsb + abase +                              \
                                  (wr * 128 + m * 16 + lrow) * 64 + kphys);   \
      s16x8 bfv[4];                                                           \
      if (b0) {                                                               \
        bfv[0] = *(const s16x8*)(ldsb + bbase +                               \
                                 (wc * 64 + 0 * 16 + lrow) * 64 + kphys);     \
        bfv[1] = *(const s16x8*)(ldsb + bbase +                               \
                                 (wc * 64 + 1 * 16 + lrow) * 64 + kphys);     \
      }                                                                       \
      if (b1) {                                                               \
        bfv[2] = *(const s16x8*)(ldsb + bbase +                               \
                                 (wc * 64 + 2 * 16 + lrow) * 64 + kphys);     \
        bfv[3] = *(const s16x8*)(ldsb + bbase +                               \
                                 (wc * 64 + 3 * 16 + lrow) * 64 + kphys);     \
      }                                                                       \
      asm volatile("s_waitcnt lgkmcnt(0)" ::: "memory");                      \
      __builtin_amdgcn_sched_barrier(0);                                      \
      __builtin_amdgcn_s_setprio(1);                                          \
      if (b0) {                                                               \
        _Pragma("unroll") for (int m = 0; m < 8; ++m) {                       \
          acc[m][0] = __builtin_amdgcn_mfma_f32_16x16x32_bf16(                \
              af[m], bfv[0], acc[m][0], 0, 0, 0);                             \
          acc[m][1] = __builtin_amdgcn_mfma_f32_16x16x32_bf16(                \
              af[m], bfv[1], acc[m][1], 0, 0, 0);                             \
        }                                                                     \
      }                                                                       \
      if (b1) {                                                               \
        _Pragma("unroll") for (int m = 0; m < 8; ++m) {                       \
          acc[m][2] = __builtin_amdgcn_mfma_f32_16x16x32_bf16(                \
              af[m], bfv[2], acc[m][2], 0, 0, 0);                             \
          acc[m][3] = __builtin_amdgcn_mfma_f32_16x16x32_bf16(                \
              af[m], bfv[3], acc[m][3], 0, 0, 0);                             \
        }                                                                     \
      }                                                                       \
      __builtin_amdgcn_s_setprio(0);                                          \
    }                                                                         \
  }

  for (int t = 0; t < NT - 2; ++t) TILE(t, "vmcnt(8)");
  TILE(NT - 2, "vmcnt(4)");
  TILE(NT - 1, "vmcnt(0)");
#undef TILE

  // Epilogue: out = 2*acc + bias. C/D frag: col = lane&15, row = g*4 + j.
#pragma unroll
  for (int n = 0; n < 4; ++n) {
    const int gcol = bn + wc * 64 + n * 16 + lrow;
    const float bv = bias[gcol];
#pragma unroll
    for (int m = 0; m < 8; ++m) {
      const int grow = bm + wr * 128 + m * 16 + (g << 2);
#pragma unroll
      for (int j = 0; j < 4; ++j)
        out[(size_t)(grow + j) * N_TOT + gcol] = 2.0f * acc[m][n][j] + bv;
    }
  }
}

// ---------------------------------------------------------------------------
// Legacy reg-staged GEMM (fallback when ws can't hold xb).
// ---------------------------------------------------------------------------
template <bool PREPPED>
__global__ __launch_bounds__(256) void gemm_kernel(
    const float* __restrict__ x, const u16* __restrict__ wb,
    const float* __restrict__ wf, const unsigned char* __restrict__ mask8,
    const float* __restrict__ bias, float* __restrict__ out) {
  __shared__ __align__(16) u16 Asl[128 * LDS_STRIDE];
  __shared__ __align__(16) u16 Bsl[128 * LDS_STRIDE];

  const int tid = threadIdx.x;
  const int lane = tid & 63;
  const int wave = tid >> 6;
  const int wr = wave >> 1;
  const int wcn = wave & 1;

  int id = blockIdx.x;
  const int cpx = gridDim.x >> 3;
  id = (id & 7) * cpx + (id >> 3);
  const int bm = (id >> 5) << 7;
  const int bn = (id & 31) << 7;

  const int arow = tid >> 4;
  const int acol = (tid & 15) << 2;
  const int brow = tid >> 3;
  const int bcol = (tid & 7) << 3;

  const int lrow = lane & 15;
  const int lgo = (lane >> 4) << 3;

  f32x4 acc[4][4] = {};

  for (int k0 = 0; k0 < K_TOT; k0 += 64) {
#pragma unroll
    for (int r = 0; r < 8; ++r) {
      const int row = arow + r * 16;
      const float4 v = *reinterpret_cast<const float4*>(
          x + (size_t)(bm + row) * K_TOT + k0 + acol);
      ushort4 bvec;
      bvec.x = f2bf(v.x); bvec.y = f2bf(v.y); bvec.z = f2bf(v.z); bvec.w = f2bf(v.w);
      *reinterpret_cast<ushort4*>(&Asl[row * LDS_STRIDE + acol]) = bvec;
    }
    if (PREPPED) {
#pragma unroll
      for (int r = 0; r < 4; ++r) {
        const int row = brow + r * 32;
        const s16x8 v = *reinterpret_cast<const s16x8*>(
            wb + (size_t)(bn + row) * K_TOT + k0 + bcol);
        *reinterpret_cast<s16x8*>(&Bsl[row * LDS_STRIDE + bcol]) = v;
      }
    } else {
#pragma unroll
      for (int r = 0; r < 8; ++r) {
        const int row = arow + r * 16;
        const float4 v = *reinterpret_cast<const float4*>(
            wf + (size_t)(bn + row) * K_TOT + k0 + acol);
        ushort4 bvec;
        bvec.x = 0; bvec.y = 0; bvec.z = 0; bvec.w = 0;
        if (mask8[((bn + row) >> 5) * MASK_DIM + ((k0 + acol) >> 5)]) {
          bvec.x = f2bf(v.x); bvec.y = f2bf(v.y); bvec.z = f2bf(v.z); bvec.w = f2bf(v.w);
        }
        *reinterpret_cast<ushort4*>(&Bsl[row * LDS_STRIDE + acol]) = bvec;
      }
    }
    __syncthreads();

#pragma unroll
    for (int ks = 0; ks < 2; ++ks) {
      s16x8 af[4], bfv[4];
#pragma unroll
      for (int m = 0; m < 4; ++m)
        af[m] = *reinterpret_cast<const s16x8*>(
            &Asl[(wr * 64 + m * 16 + lrow) * LDS_STRIDE + ks * 32 + lgo]);
#pragma unroll
      for (int n = 0; n < 4; ++n)
        bfv[n] = *reinterpret_cast<const s16x8*>(
            &Bsl[(wcn * 64 + n * 16 + lrow) * LDS_STRIDE + ks * 32 + lgo]);
#pragma unroll
      for (int m = 0; m < 4; ++m)
#pragma unroll
        for (int n = 0; n < 4; ++n)
          acc[m][n] = __builtin_amdgcn_mfma_f32_16x16x32_bf16(af[m], bfv[n],
                                                              acc[m][n], 0, 0, 0);
    }
    __syncthreads();
  }

#pragma unroll
  for (int n = 0; n < 4; ++n) {
    const int gcol = bn + wcn * 64 + n * 16 + lrow;
    const float bv = bias[gcol];
#pragma unroll
    for (int m = 0; m < 4; ++m) {
      const int grow = bm + wr * 64 + m * 16 + ((lane >> 4) << 2);
#pragma unroll
      for (int j = 0; j < 4; ++j) {
        out[(size_t)(grow + j) * N_TOT + gcol] = 2.0f * acc[m][n][j] + bv;
      }
    }
  }
}

extern "C" void kernel_launch(void* const* d_in, const int* in_sizes, int n_in,
                              void* d_out, int out_size, void* d_ws, size_t ws_size,
                              hipStream_t stream) {
  const float* x = (const float*)d_in[0];
  const float* w = (const float*)d_in[1];
  const float* bias = (const float*)d_in[2];
  const unsigned char* mask_raw = (const unsigned char*)d_in[3];
  float* out = (float*)d_out;

  unsigned char* ws_mask = (unsigned char*)d_ws;            // 16 KiB mask8
  unsigned* ws_bits = (unsigned*)((char*)d_ws + 16384);     // 2 KiB bitmask
  u16* wb = (u16*)((char*)d_ws + 65536);                    // 32 MiB bf16 W
  u16* xb = (u16*)((char*)d_ws + 65536 +
                   (size_t)N_TOT * K_TOT * sizeof(u16));    // 128 MiB bf16 x
  const size_t need_w = 65536 + (size_t)N_TOT * K_TOT * sizeof(u16);
  const size_t need_full = need_w + (size_t)M_TOT * K_TOT * sizeof(u16);

  prep_mask_kernel<<<1, 256, 0, stream>>>(mask_raw, ws_mask, ws_bits);

  if (ws_size >= need_full) {
    prep_w_swz_kernel<<<(N_TOT * (K_TOT / 8)) / 256, 256, 0, stream>>>(w, ws_mask, wb);
    prep_x_swz_kernel<<<(M_TOT * (K_TOT / 8)) / 256, 256, 0, stream>>>(x, xb);
    hipFuncSetAttribute(reinterpret_cast<const void*>(gemm8_kernel),
                        hipFuncAttributeMaxDynamicSharedMemorySize, 131072);
    gemm8_kernel<<<(M_TOT / 256) * (N_TOT / 256), 512, 131072, stream>>>(
        xb, wb, ws_bits, bias, out);
  } else if (ws_size >= need_w) {
    prep_w_kernel<<<(N_TOT * K_TOT) / (256 * 4), 256, 0, stream>>>(w, ws_mask, wb);
    gemm_kernel<true><<<(M_TOT / 128) * (N_TOT / 128), 256, 0, stream>>>(
        x, wb, nullptr, nullptr, bias, out);
  } else {
    gemm_kernel<false><<<(M_TOT / 128) * (N_TOT / 128), 256, 0, stream>>>(
        x, nullptr, w, ws_mask, bias, out);
  }
}